// Round 13
// baseline (89.585 us; speedup 1.0000x reference)
//
#include <hip/hip_runtime.h>

#define GAMMA 0.1f
#define ETA   0.3f
#define ITERS 2   // 64-row chunks per wave — R10 schedule (84.9 us anchor)

typedef __attribute__((ext_vector_type(8))) short short8;
typedef __attribute__((ext_vector_type(4))) float f32x4;

__device__ __forceinline__ short f2bf(float x) {
    // round-to-nearest-even fp32 -> bf16 payload (R2/R10-proven)
    unsigned u = __float_as_uint(x);
    u += 0x7FFFu + ((u >> 16) & 1u);
    return (short)(u >> 16);
}

// EXACT R10 body (84.9 us, PASS) with ONE substitution: persistent weight
// registers u/v/bb/b2a/lnwa/lnba -> typed fp32 LDS arrays with scalar
// indexing (no reinterpret_cast on LDS, no f16, no bit_cast — the two
// failing rounds' common ingredients are all removed). Staging is trivial:
// s_uf[k] = W1[k]+W1[128+k] etc. Persistent VGPR: wfrag(16) only; target
// <=64 total -> 8 waves/SIMD (2x latency hiding vs R10's 4).
__global__ __launch_bounds__(256) void market_impact_mfma(
    const float* __restrict__ os_g, const float* __restrict__ liq_g,
    const float* __restrict__ W1,  const float* __restrict__ b1g,
    const float* __restrict__ W2,  const float* __restrict__ b2,
    const float* __restrict__ lnw, const float* __restrict__ lnb,
    float* __restrict__ out, int B)
{
    __shared__ __align__(16) float s_uf[64], s_vf[64], s_bf[64];
    __shared__ __align__(16) float s_b2f[32], s_lwf[32], s_lbf[32];

    const int tid  = threadIdx.x;
    const int lane = tid & 63;
    const int g    = lane >> 4;   // k-group (0..3)
    const int c    = lane & 15;   // A row = out col (16-block); B col = data row

    // ---- stage weights to LDS: typed scalar stores, trivially checkable ----
    if (tid < 64) {
        float w2r = W1[128 + tid];
        s_uf[tid] = W1[tid]      + w2r;   // u[k] = W1[0][k] + W1[2][k]
        s_vf[tid] = W1[64 + tid] + w2r;   // v[k] = W1[1][k] + W1[2][k]
        s_bf[tid] = b1g[tid];
    } else if (tid < 96) {
        s_b2f[tid - 64] = b2[tid - 64];
    } else if (tid < 128) {
        s_lwf[tid - 96] = lnw[tid - 96];
    } else if (tid < 160) {
        s_lbf[tid - 128] = lnb[tid - 128];
    }

    // W2^T fragments (A-operand, bf16, 16 VGPR) — unchanged from R10
    short8 wfrag[2][2];
    #pragma unroll
    for (int kc = 0; kc < 2; ++kc)
        #pragma unroll
        for (int cc = 0; cc < 2; ++cc) {
            short8 t;
            #pragma unroll
            for (int j = 0; j < 8; ++j) {
                int k = kc * 32 + g * 8 + j;
                t[j] = f2bf(W2[k * 32 + cc * 16 + c]);
            }
            wfrag[kc][cc] = t;
        }

    __syncthreads();

    const long long wid = (long long)blockIdx.x * 4 + (tid >> 6);
    float* enc = out + 3LL * B;

    #pragma unroll 1
    for (int it = 0; it < ITERS; ++it) {
        long long base = (wid * ITERS + it) * 64;
        if (base >= B) break;                      // wave-uniform

        int r  = (int)base + lane;
        bool ok = r < B;
        float o  = ok ? os_g[r]  : 0.f;
        float lq = ok ? liq_g[r] : 1.f;
        float perm = GAMMA * o / lq;               // exact (R2-proven)
        float temp = ETA * copysignf(sqrtf(fabsf(o)), o) * rsqrtf(lq);
        float tot  = perm + temp;
        if (ok) {
            __builtin_nontemporal_store(perm, &out[r]);
            __builtin_nontemporal_store(temp, &out[B + r]);
            __builtin_nontemporal_store(tot,  &out[2 * B + r]);
        }

        #pragma unroll
        for (int mt = 0; mt < 4; ++mt) {
            // B-operand: h for row base + mt*16 + c, k = kc*32 + g*8 + j
            float pm = __shfl(perm, mt * 16 + c);
            float tm = __shfl(temp, mt * 16 + c);
            short8 a0, a1;
            #pragma unroll
            for (int j = 0; j < 8; ++j) {
                int k0 = g * 8 + j;          // kc=0
                int k1 = 32 + g * 8 + j;     // kc=1
                float h0 = fmaxf(0.f, fmaf(pm, s_uf[k0], fmaf(tm, s_vf[k0], s_bf[k0])));
                float h1 = fmaxf(0.f, fmaf(pm, s_uf[k1], fmaf(tm, s_vf[k1], s_bf[k1])));
                a0[j] = f2bf(h0);
                a1[j] = f2bf(h1);
            }

            f32x4 d0 = {0.f, 0.f, 0.f, 0.f};
            f32x4 d1 = {0.f, 0.f, 0.f, 0.f};
            d0 = __builtin_amdgcn_mfma_f32_16x16x32_bf16(wfrag[0][0], a0, d0, 0, 0, 0);
            d0 = __builtin_amdgcn_mfma_f32_16x16x32_bf16(wfrag[1][0], a1, d0, 0, 0, 0);
            d1 = __builtin_amdgcn_mfma_f32_16x16x32_bf16(wfrag[0][1], a0, d1, 0, 0, 0);
            d1 = __builtin_amdgcn_mfma_f32_16x16x32_bf16(wfrag[1][1], a1, d1, 0, 0, 0);

            // x = d + b2 (epilogue add, as R10); lane holds row (base+mt*16+c),
            // cols cc*16 + g*4 + reg
            float x[8];
            #pragma unroll
            for (int reg = 0; reg < 4; ++reg) {
                x[reg]     = d0[reg] + s_b2f[g * 4 + reg];
                x[4 + reg] = d1[reg] + s_b2f[16 + g * 4 + reg];
            }
            float s = 0.f, q = 0.f;
            #pragma unroll
            for (int j = 0; j < 8; ++j) { s += x[j]; q = fmaf(x[j], x[j], q); }
            s += __shfl_xor(s, 16); s += __shfl_xor(s, 32);
            q += __shfl_xor(q, 16); q += __shfl_xor(q, 32);
            float mu   = s * 0.03125f;
            float var  = fmaf(q, 0.03125f, -mu * mu);
            float rstd = rsqrtf(var + 1e-5f);

            int row = (int)base + mt * 16 + c;
            if (row < B) {
                f32x4 o0, o1;
                #pragma unroll
                for (int reg = 0; reg < 4; ++reg) {
                    o0[reg] = fmaf((x[reg] - mu) * rstd,
                                   s_lwf[g * 4 + reg],      s_lbf[g * 4 + reg]);
                    o1[reg] = fmaf((x[4 + reg] - mu) * rstd,
                                   s_lwf[16 + g * 4 + reg], s_lbf[16 + g * 4 + reg]);
                }
                float* rp = enc + (long long)row * 32;
                __builtin_nontemporal_store(o0, reinterpret_cast<f32x4*>(rp + g * 4));
                __builtin_nontemporal_store(o1, reinterpret_cast<f32x4*>(rp + 16 + g * 4));
            }
        }
    }
}

extern "C" void kernel_launch(void* const* d_in, const int* in_sizes, int n_in,
                              void* d_out, int out_size, void* d_ws, size_t ws_size,
                              hipStream_t stream) {
    const float* os_g = (const float*)d_in[0];
    const float* liq  = (const float*)d_in[1];
    const float* W1   = (const float*)d_in[2];
    const float* b1   = (const float*)d_in[3];
    const float* W2   = (const float*)d_in[4];
    const float* b2   = (const float*)d_in[5];
    const float* lnw  = (const float*)d_in[6];
    const float* lnb  = (const float*)d_in[7];
    float* out = (float*)d_out;
    const int B = in_sizes[0];

    const int rows_per_block = 4 * ITERS * 64;   // 512
    const int grid = (B + rows_per_block - 1) / rows_per_block;   // 3907 @ B=2M
    market_impact_mfma<<<grid, 256, 0, stream>>>(
        os_g, liq, W1, b1, W2, b2, lnw, lnb, out, B);
}

// Round 14
// 85.146 us; speedup vs baseline: 1.0521x; 1.0521x over previous
//
#include <hip/hip_runtime.h>

#define GAMMA 0.1f
#define ETA   0.3f
#define ITERS 2   // 64-row chunks per wave

typedef __attribute__((ext_vector_type(8))) short short8;
typedef __attribute__((ext_vector_type(4))) float f32x4;

__device__ __forceinline__ short f2bf(float x) {
    // round-to-nearest-even fp32 -> bf16 payload (R2/R10/R13-proven)
    unsigned u = __float_as_uint(x);
    u += 0x7FFFu + ((u >> 16) & 1u);
    return (short)(u >> 16);
}

// R13 base (LDS weights, typed scalar indexing — PASSED 89.6us) with a
// register-occupancy push: __launch_bounds__(256,6) caps VGPR at 85
// (512-reg SIMD file / 6 waves). Working-set cuts to fit safely:
//   - b2 joins via MFMA C-init (typed scalar LDS reads; exact fp32) — kills
//     the x[8] epilogue array (-8 VGPR).
//   - a0 consumed by both its MFMAs before a1 is built (-4 VGPR).
// Theory: 85us plateau = store-retirement stalls (s_waitcnt vmcnt before
// store-source reg reuse); 6 waves/SIMD instead of 4 hides them.
// NT stores kept (R10-proven). No vector-punned LDS reads (R11/R12 lesson).
__global__ __launch_bounds__(256, 6) void market_impact_mfma(
    const float* __restrict__ os_g, const float* __restrict__ liq_g,
    const float* __restrict__ W1,  const float* __restrict__ b1g,
    const float* __restrict__ W2,  const float* __restrict__ b2,
    const float* __restrict__ lnw, const float* __restrict__ lnb,
    float* __restrict__ out, int B)
{
    __shared__ __align__(16) float s_uf[64], s_vf[64], s_bf[64];
    __shared__ __align__(16) float s_b2f[32], s_lwf[32], s_lbf[32];

    const int tid  = threadIdx.x;
    const int lane = tid & 63;
    const int g    = lane >> 4;   // k-group (0..3)
    const int c    = lane & 15;   // A row = out col (16-block); B col = data row

    // ---- stage weights to LDS: typed scalar stores (R13-proven) ----
    if (tid < 64) {
        float w2r = W1[128 + tid];
        s_uf[tid] = W1[tid]      + w2r;   // u[k] = W1[0][k] + W1[2][k]
        s_vf[tid] = W1[64 + tid] + w2r;   // v[k] = W1[1][k] + W1[2][k]
        s_bf[tid] = b1g[tid];
    } else if (tid < 96) {
        s_b2f[tid - 64] = b2[tid - 64];
    } else if (tid < 128) {
        s_lwf[tid - 96] = lnw[tid - 96];
    } else if (tid < 160) {
        s_lbf[tid - 128] = lnb[tid - 128];
    }

    // W2^T fragments (A-operand, bf16, 16 VGPR)
    short8 wfrag[2][2];
    #pragma unroll
    for (int kc = 0; kc < 2; ++kc)
        #pragma unroll
        for (int cc = 0; cc < 2; ++cc) {
            short8 t;
            #pragma unroll
            for (int j = 0; j < 8; ++j) {
                int k = kc * 32 + g * 8 + j;
                t[j] = f2bf(W2[k * 32 + cc * 16 + c]);
            }
            wfrag[kc][cc] = t;
        }

    __syncthreads();

    const long long wid = (long long)blockIdx.x * 4 + (tid >> 6);
    float* enc = out + 3LL * B;

    #pragma unroll 1
    for (int it = 0; it < ITERS; ++it) {
        long long base = (wid * ITERS + it) * 64;
        if (base >= B) break;                      // wave-uniform

        int r  = (int)base + lane;
        bool ok = r < B;
        float o  = ok ? os_g[r]  : 0.f;
        float lq = ok ? liq_g[r] : 1.f;
        float perm = GAMMA * o / lq;               // exact
        float temp = ETA * copysignf(sqrtf(fabsf(o)), o) * rsqrtf(lq);
        float tot  = perm + temp;
        if (ok) {
            __builtin_nontemporal_store(perm, &out[r]);
            __builtin_nontemporal_store(temp, &out[B + r]);
            __builtin_nontemporal_store(tot,  &out[2 * B + r]);
        }

        #pragma unroll
        for (int mt = 0; mt < 4; ++mt) {
            float pm = __shfl(perm, mt * 16 + c);
            float tm = __shfl(temp, mt * 16 + c);

            // C-init = b2 (typed scalar LDS reads; exact fp32 bias)
            f32x4 d0 = { s_b2f[g * 4 + 0], s_b2f[g * 4 + 1],
                         s_b2f[g * 4 + 2], s_b2f[g * 4 + 3] };
            f32x4 d1 = { s_b2f[16 + g * 4 + 0], s_b2f[16 + g * 4 + 1],
                         s_b2f[16 + g * 4 + 2], s_b2f[16 + g * 4 + 3] };

            // kc=0: build a0, consume immediately (a0 dead before a1 built)
            {
                short8 a0;
                #pragma unroll
                for (int j = 0; j < 8; ++j) {
                    int k = g * 8 + j;
                    a0[j] = f2bf(fmaxf(0.f,
                              fmaf(pm, s_uf[k], fmaf(tm, s_vf[k], s_bf[k]))));
                }
                d0 = __builtin_amdgcn_mfma_f32_16x16x32_bf16(wfrag[0][0], a0, d0, 0, 0, 0);
                d1 = __builtin_amdgcn_mfma_f32_16x16x32_bf16(wfrag[0][1], a0, d1, 0, 0, 0);
            }
            // kc=1
            {
                short8 a1;
                #pragma unroll
                for (int j = 0; j < 8; ++j) {
                    int k = 32 + g * 8 + j;
                    a1[j] = f2bf(fmaxf(0.f,
                              fmaf(pm, s_uf[k], fmaf(tm, s_vf[k], s_bf[k]))));
                }
                d0 = __builtin_amdgcn_mfma_f32_16x16x32_bf16(wfrag[1][0], a1, d0, 0, 0, 0);
                d1 = __builtin_amdgcn_mfma_f32_16x16x32_bf16(wfrag[1][1], a1, d1, 0, 0, 0);
            }

            // LN over 32 cols: lane holds row (base+mt*16+c), cols cc*16+g*4+reg
            float s = 0.f, q = 0.f;
            #pragma unroll
            for (int reg = 0; reg < 4; ++reg) {
                s += d0[reg];  q = fmaf(d0[reg], d0[reg], q);
                s += d1[reg];  q = fmaf(d1[reg], d1[reg], q);
            }
            s += __shfl_xor(s, 16); s += __shfl_xor(s, 32);
            q += __shfl_xor(q, 16); q += __shfl_xor(q, 32);
            float mu   = s * 0.03125f;
            float var  = fmaf(q, 0.03125f, -mu * mu);
            float rstd = rsqrtf(var + 1e-5f);

            int row = (int)base + mt * 16 + c;
            if (row < B) {
                f32x4 o0, o1;
                #pragma unroll
                for (int reg = 0; reg < 4; ++reg) {
                    o0[reg] = fmaf((d0[reg] - mu) * rstd,
                                   s_lwf[g * 4 + reg],      s_lbf[g * 4 + reg]);
                    o1[reg] = fmaf((d1[reg] - mu) * rstd,
                                   s_lwf[16 + g * 4 + reg], s_lbf[16 + g * 4 + reg]);
                }
                float* rp = enc + (long long)row * 32;
                __builtin_nontemporal_store(o0, reinterpret_cast<f32x4*>(rp + g * 4));
                __builtin_nontemporal_store(o1, reinterpret_cast<f32x4*>(rp + 16 + g * 4));
            }
        }
    }
}

extern "C" void kernel_launch(void* const* d_in, const int* in_sizes, int n_in,
                              void* d_out, int out_size, void* d_ws, size_t ws_size,
                              hipStream_t stream) {
    const float* os_g = (const float*)d_in[0];
    const float* liq  = (const float*)d_in[1];
    const float* W1   = (const float*)d_in[2];
    const float* b1   = (const float*)d_in[3];
    const float* W2   = (const float*)d_in[4];
    const float* b2   = (const float*)d_in[5];
    const float* lnw  = (const float*)d_in[6];
    const float* lnb  = (const float*)d_in[7];
    float* out = (float*)d_out;
    const int B = in_sizes[0];

    const int rows_per_block = 4 * ITERS * 64;   // 512
    const int grid = (B + rows_per_block - 1) / rows_per_block;   // 3907 @ B=2M
    market_impact_mfma<<<grid, 256, 0, stream>>>(
        os_g, liq, W1, b1, W2, b2, lnw, lnb, out, B);
}